// Round 4
// baseline (107.858 us; speedup 1.0000x reference)
//
#include <hip/hip_runtime.h>

// ModulatedDeformConv2d fwd — wave-autonomous register-direct design:
//   xtrans:  x NCHW fp32 -> xT NHWC bf16 (one bilinear neighbor = 128 contiguous B)
//   wtrans2: weight -> wbfA in exact MFMA A-fragment order (16B/lane coalesced)
//   dcn2:    per-wave 16px x 64o tile; bilinear gather lands directly in MFMA
//            B-fragment registers. NO LDS, NO barriers in the hot kernel.
// B=4 C=64 H=W=96 O=64 K=3x3 stride=1 pad=1 dil=1 groups=1 dg=1
#define Bn 4
#define Cn 64
#define Hn 96
#define Wn 96
#define On 64
#define Kn 9
#define HWn (Hn*Wn)
#define NT 256
#define KT (Kn*Cn)          // 576 = GEMM K
#define TW (Wn/16)          // 6 pixel-tiles per row
#define NTILES (Bn*Hn*TW)   // 2304 waves total
#define NBLK (NTILES/4)     // 576 blocks of 4 waves

typedef __attribute__((ext_vector_type(8))) short bf16x8;
typedef __attribute__((ext_vector_type(4))) float f32x4;

__device__ __forceinline__ unsigned short f2bf(float f) {
    unsigned u = __float_as_uint(f);
    u += 0x7FFFu + ((u >> 16) & 1u);   // RNE; inputs finite
    return (unsigned short)(u >> 16);
}
__device__ __forceinline__ float bf2f(unsigned short h) {
    return __uint_as_float((unsigned)h << 16);
}

// wbfA fragment order: frag (t=K-window 0..17, ot=o-tile 0..3), lane l:
//   A[o = ot*16 + (l&15)][kappa = t*32 + (l>>4)*8 + j], j=0..7, kappa = k*64+c.
__global__ void wtrans2_kernel(const float* __restrict__ w, unsigned short* __restrict__ wbfA) {
    int i = blockIdx.x * NT + threadIdx.x;
    if (i < 18 * 4 * 64 * 8) {
        int j  = i & 7;
        int l  = (i >> 3) & 63;
        int ot = (i >> 9) & 3;
        int t  = i >> 11;
        int o  = ot * 16 + (l & 15);
        int kp = t * 32 + (l >> 4) * 8 + j;
        wbfA[i] = f2bf(w[(o * Cn + (kp & 63)) * Kn + (kp >> 6)]);
    }
}

// xT[b][h][w][c] = bf16(x[b][c][h][w])
__global__ __launch_bounds__(NT) void xtrans_kernel(const float* __restrict__ x,
                                                    unsigned short* __restrict__ xT) {
    __shared__ unsigned short tile[Cn * Wn];   // 12 KB
    const int tid = threadIdx.x;
    const int b = blockIdx.x / Hn;
    const int h = blockIdx.x - b * Hn;
    #pragma unroll
    for (int i = 0; i < (Cn * Wn) / NT; ++i) {
        int e = i * NT + tid;
        int c = e / Wn, w = e - c * Wn;
        tile[c * Wn + w] = f2bf(x[(((size_t)b * Cn + c) * Hn + h) * Wn + w]);
    }
    __syncthreads();
    #pragma unroll
    for (int i = 0; i < (Wn * 8) / NT; ++i) {
        int s = i * NT + tid;
        int w = s >> 3, g = s & 7;
        unsigned short hh[8];
        #pragma unroll
        for (int j = 0; j < 8; ++j) hh[j] = tile[(g * 8 + j) * Wn + w];
        uint4 pk;
        pk.x = hh[0] | ((unsigned)hh[1] << 16);
        pk.y = hh[2] | ((unsigned)hh[3] << 16);
        pk.z = hh[4] | ((unsigned)hh[5] << 16);
        pk.w = hh[6] | ((unsigned)hh[7] << 16);
        *(uint4*)&xT[(((size_t)b * Hn + h) * Wn + w) * Cn + g * 8] = pk;
    }
}

__global__ __launch_bounds__(NT) void dcn2_kernel(
    const unsigned short* __restrict__ xT, const float* __restrict__ offset,
    const float* __restrict__ mask, const float* __restrict__ bias,
    const unsigned short* __restrict__ wbfA, float* __restrict__ out)
{
    const int tid  = threadIdx.x;
    const int wave = tid >> 6;
    const int lane = tid & 63;
    const int n    = lane & 15;   // pixel within tile (= MFMA col)
    const int quad = lane >> 4;   // k-slice owner
    const int qo   = quad * 8;    // channel octet offset within window

    // XCD swizzle: each XCD gets a contiguous 72-block (=48 rows of one batch) span.
    const int p = blockIdx.x;
    const int v = (p & 7) * (NBLK / 8) + (p >> 3);
    const int T = v * 4 + wave;                    // tile id 0..2303
    const int b  = T / (Hn * TW);
    int rem      = T - b * (Hn * TW);
    const int ho = rem / TW;
    const int wt = rem - ho * TW;
    const int wo0 = wt * 16;
    const int wo  = wo0 + n;

    const unsigned short* xb = xT + (size_t)b * HWn * Cn;
    const bf16x8* Af = (const bf16x8*)wbfA;
    const size_t obase = ((size_t)b * 2 * Kn) * HWn + (size_t)ho * Wn + wo;
    const size_t mbase = ((size_t)b * Kn) * HWn + (size_t)ho * Wn + wo;

    f32x4 acc[4] = {{0.f,0.f,0.f,0.f},{0.f,0.f,0.f,0.f},
                    {0.f,0.f,0.f,0.f},{0.f,0.f,0.f,0.f}};

    #pragma unroll
    for (int k = 0; k < Kn; ++k) {
        // per-(pixel, tap) bilinear table (computed redundantly per quad; cheap)
        float oy = offset[obase + (size_t)(2 * k) * HWn];
        float ox = offset[obase + (size_t)(2 * k + 1) * HWn];
        float mm = mask  [mbase + (size_t)k * HWn];
        float py = (float)(ho - 1 + (k / 3)) + oy;
        float px = (float)(wo - 1 + (k % 3)) + ox;
        float y0f = floorf(py), x0f = floorf(px);
        float ly = py - y0f, lx = px - x0f;
        int y0 = (int)y0f, x0i = (int)x0f;
        int y1 = y0 + 1,   x1i = x0i + 1;
        float vy0 = (y0  >= 0 && y0  < Hn) ? 1.f : 0.f;
        float vy1 = (y1  >= 0 && y1  < Hn) ? 1.f : 0.f;
        float vx0 = (x0i >= 0 && x0i < Wn) ? 1.f : 0.f;
        float vx1 = (x1i >= 0 && x1i < Wn) ? 1.f : 0.f;
        int cy0 = min(max(y0, 0),  Hn-1), cy1 = min(max(y1, 0),  Hn-1);
        int cx0 = min(max(x0i, 0), Wn-1), cx1 = min(max(x1i, 0), Wn-1);
        float w0 = (1.f - ly) * (1.f - lx) * mm * vy0 * vx0;
        float w1 = (1.f - ly) * lx         * mm * vy0 * vx1;
        float w2 = ly         * (1.f - lx) * mm * vy1 * vx0;
        float w3 = ly         * lx         * mm * vy1 * vx1;

        // gather 4 neighbors x 2 channel-octets (16B coalesced loads)
        const unsigned short* r0 = xb + ((size_t)(cy0 * Wn + cx0) << 6) + qo;
        const unsigned short* r1 = xb + ((size_t)(cy0 * Wn + cx1) << 6) + qo;
        const unsigned short* r2 = xb + ((size_t)(cy1 * Wn + cx0) << 6) + qo;
        const unsigned short* r3 = xb + ((size_t)(cy1 * Wn + cx1) << 6) + qo;
        bf16x8 v00 = *(const bf16x8*)r0,  v01 = *(const bf16x8*)(r0 + 32);
        bf16x8 v10 = *(const bf16x8*)r1,  v11 = *(const bf16x8*)(r1 + 32);
        bf16x8 v20 = *(const bf16x8*)r2,  v21 = *(const bf16x8*)(r2 + 32);
        bf16x8 v30 = *(const bf16x8*)r3,  v31 = *(const bf16x8*)(r3 + 32);

        // combine -> two B-fragments (windows t=2k, 2k+1) directly in registers
        bf16x8 b0, b1;
        #pragma unroll
        for (int j = 0; j < 8; ++j) {
            float f0 = w0 * bf2f((unsigned short)v00[j]) + w1 * bf2f((unsigned short)v10[j])
                     + w2 * bf2f((unsigned short)v20[j]) + w3 * bf2f((unsigned short)v30[j]);
            float f1 = w0 * bf2f((unsigned short)v01[j]) + w1 * bf2f((unsigned short)v11[j])
                     + w2 * bf2f((unsigned short)v21[j]) + w3 * bf2f((unsigned short)v31[j]);
            b0[j] = (short)f2bf(f0);
            b1[j] = (short)f2bf(f1);
        }

        const int t0 = 2 * k, t1 = 2 * k + 1;
        #pragma unroll
        for (int ot = 0; ot < 4; ++ot) {
            bf16x8 a0 = Af[(t0 * 4 + ot) * 64 + lane];
            acc[ot] = __builtin_amdgcn_mfma_f32_16x16x32_bf16(a0, b0, acc[ot], 0, 0, 0);
        }
        #pragma unroll
        for (int ot = 0; ot < 4; ++ot) {
            bf16x8 a1 = Af[(t1 * 4 + ot) * 64 + lane];
            acc[ot] = __builtin_amdgcn_mfma_f32_16x16x32_bf16(a1, b1, acc[ot], 0, 0, 0);
        }
    }

    // Epilogue: C/D layout col=lane&15 (=pixel n), row=quad*4+r within 16-o tile.
    #pragma unroll
    for (int ot = 0; ot < 4; ++ot) {
        #pragma unroll
        for (int r = 0; r < 4; ++r) {
            int o = ot * 16 + quad * 4 + r;
            out[(((size_t)b * On + o) * Hn + ho) * Wn + wo0 + n] = acc[ot][r] + bias[o];
        }
    }
}

// Correct-but-slow fallback (only if workspace is too small; never expected).
__global__ __launch_bounds__(NT) void dcn_fallback_kernel(
    const float* __restrict__ x, const float* __restrict__ offset,
    const float* __restrict__ mask, const float* __restrict__ weight,
    const float* __restrict__ bias, float* __restrict__ out)
{
    int idx = blockIdx.x * NT + threadIdx.x;
    if (idx >= Bn * On * HWn) return;
    int wo = idx % Wn;
    int ho = (idx / Wn) % Hn;
    int o  = (idx / HWn) % On;
    int b  = idx / (On * HWn);
    float s = bias[o];
    for (int k = 0; k < Kn; ++k) {
        float oy = offset[((b * (2*Kn) + 2*k    ) * Hn + ho) * Wn + wo];
        float ox = offset[((b * (2*Kn) + 2*k + 1) * Hn + ho) * Wn + wo];
        float mm = mask  [((b * Kn + k) * Hn + ho) * Wn + wo];
        float py = (float)(ho - 1 + (k / 3)) + oy;
        float px = (float)(wo - 1 + (k % 3)) + ox;
        float y0f = floorf(py), x0f = floorf(px);
        float ly = py - y0f, lx = px - x0f;
        int y0 = (int)y0f, x0i = (int)x0f, y1 = y0 + 1, x1i = x0i + 1;
        float vy0 = (y0  >= 0 && y0  < Hn) ? 1.f : 0.f;
        float vy1 = (y1  >= 0 && y1  < Hn) ? 1.f : 0.f;
        float vx0 = (x0i >= 0 && x0i < Wn) ? 1.f : 0.f;
        float vx1 = (x1i >= 0 && x1i < Wn) ? 1.f : 0.f;
        int cy0 = min(max(y0, 0),  Hn-1), cy1 = min(max(y1, 0),  Hn-1);
        int cx0 = min(max(x0i, 0), Wn-1), cx1 = min(max(x1i, 0), Wn-1);
        float w0 = (1.f-ly)*(1.f-lx)*mm*vy0*vx0, w1 = (1.f-ly)*lx*mm*vy0*vx1;
        float w2 = ly*(1.f-lx)*mm*vy1*vx0,       w3 = ly*lx*mm*vy1*vx1;
        int i0 = cy0*Wn+cx0, i1 = cy0*Wn+cx1, i2 = cy1*Wn+cx0, i3 = cy1*Wn+cx1;
        for (int c = 0; c < Cn; ++c) {
            const float* xp = x + ((size_t)b * Cn + c) * HWn;
            float vv = w0*xp[i0] + w1*xp[i1] + w2*xp[i2] + w3*xp[i3];
            s += vv * weight[(o * Cn + c) * Kn + k];
        }
    }
    out[idx] = s;
}

extern "C" void kernel_launch(void* const* d_in, const int* in_sizes, int n_in,
                              void* d_out, int out_size, void* d_ws, size_t ws_size,
                              hipStream_t stream) {
    const float* x      = (const float*)d_in[0];
    const float* offset = (const float*)d_in[1];
    const float* mask   = (const float*)d_in[2];
    const float* weight = (const float*)d_in[3];
    const float* bias   = (const float*)d_in[4];
    float* out = (float*)d_out;

    const size_t xt_bytes = (size_t)Bn * HWn * Cn * sizeof(unsigned short);  // 4.7 MB
    const size_t w_bytes  = (size_t)18 * 4 * 64 * 8 * sizeof(unsigned short); // 73728 B

    if (ws_size >= xt_bytes + w_bytes) {
        unsigned short* xT   = (unsigned short*)d_ws;
        unsigned short* wbfA = (unsigned short*)((char*)d_ws + xt_bytes);
        wtrans2_kernel<<<(18*4*64*8 + NT - 1) / NT, NT, 0, stream>>>(weight, wbfA);
        xtrans_kernel<<<Bn * Hn, NT, 0, stream>>>(x, xT);
        dcn2_kernel<<<NBLK, NT, 0, stream>>>(xT, offset, mask, bias, wbfA, out);
    } else {
        dcn_fallback_kernel<<<(Bn * On * HWn + NT - 1) / NT, NT, 0, stream>>>(
            x, offset, mask, weight, bias, out);
    }
}